// Round 6
// baseline (312.348 us; speedup 1.0000x reference)
//
#include <hip/hip_runtime.h>

#define HH 384
#define WW 640
#define OHH 382
#define NPLANES 96
#define NCHUNK 3     // load-col starts {0,252,504}; dwordx4 per lane, shuffle for +2
#define NSTRIP 32    // 32 strips x RPS=12 = 384 rows exact
#define RPS 12
#define NBLOCKS 2304 // 96*3*32 waves / 4 = 2304 = 8*288 (bijective XCD swizzle)

// ssim denom = 16*3*382*638 = 11,698,368 ; l1 denom = 16*3*384*640 = 11,796,480

typedef float f4 __attribute__((ext_vector_type(4)));

#define C1 0.0162f   // 162 * K1
#define C2 0.1458f   // 162 * K2

__device__ __forceinline__ float rcpf_(float x) { return __builtin_amdgcn_rcpf(x); }

__global__ __launch_bounds__(256, 6) void ssim_main(const float* __restrict__ X,
                                                    const float* __restrict__ Y,
                                                    float* __restrict__ ws) {
    const int lane = threadIdx.x & 63;
    const int wv   = threadIdx.x >> 6;
    const int bid0 = blockIdx.x;
    const int bid  = (bid0 & 7) * 288 + (bid0 >> 3);   // XCD-contiguous remap
    const int wid  = bid * 4 + wv;                     // block = 4 adjacent strips

    const int strip = wid & 31;
    const int pc    = wid >> 5;
    const int chunk = pc % NCHUNK;
    const int p     = pc / NCHUNK;

    const int a  = chunk * 252;
    const int c0 = a + (lane << 2);                    // nominal first col (unclamped)
    const int cL = (c0 <= 636) ? c0 : 636;             // clamped load col (chunk2 tail dups)
    const int r0 = strip * RPS;

    const size_t pb = (size_t)p * (HH * WW);
    const float* __restrict__ xb = X + pb + cL;
    const float* __restrict__ yb = Y + pb + cL;

#define LDX(ROW) (*(const f4*)(xb + (size_t)(ROW) * WW))
#define LDY(ROW) (*(const f4*)(yb + (size_t)(ROW) * WW))

    f4 accs = {0.f,0.f,0.f,0.f};
    f4 accl = {0.f,0.f,0.f,0.f};
    f4 rx[4], ry[4];                                   // row ring; all indices static
    f4 h0u,h0v,h0p,h0q, h1u,h1v,h1p,h1q;

// horizontal pass over lane's 4 cols (+2 via shuffle). L1 accumulated UNMASKED;
// ownership applied once at epilogue (saves 8 VGPR + 8 VALU/iter in the loop).
#define HROW(XV, YV, HU, HV, HP, HQ, DOL1) do {                                \
    f4 u = (XV) + (YV);                                                        \
    f4 v = (XV) - (YV);                                                        \
    if (DOL1) {                                                                \
        accl.x += fabsf(v.x); accl.y += fabsf(v.y);                            \
        accl.z += fabsf(v.z); accl.w += fabsf(v.w);                            \
    }                                                                          \
    float u4 = __shfl_down(u.x,1), u5 = __shfl_down(u.y,1);                    \
    float v4 = __shfl_down(v.x,1), v5 = __shfl_down(v.y,1);                    \
    f4 pp = u*u, qq = v*v;                                                     \
    float p4 = u4*u4, p5 = u5*u5, q4 = v4*v4, q5 = v5*v5;                      \
    HU = (f4){u.x+u.y+u.z, u.y+u.z+u.w, u.z+u.w+u4, u.w+u4+u5};                \
    HV = (f4){v.x+v.y+v.z, v.y+v.z+v.w, v.z+v.w+v4, v.w+v4+v5};                \
    HP = (f4){pp.x+pp.y+pp.z, pp.y+pp.z+pp.w, pp.z+pp.w+p4, pp.w+p4+p5};       \
    HQ = (f4){qq.x+qq.y+qq.z, qq.y+qq.z+qq.w, qq.z+qq.w+q4, qq.w+q4+q5};       \
} while (0)

    // prologue: rows r0..r0+3 into ring slots 0..3 (r0 % 4 == 0)
    rx[0] = LDX(r0);     ry[0] = LDY(r0);
    rx[1] = LDX(r0 + 1); ry[1] = LDY(r0 + 1);
    rx[2] = LDX(r0 + 2); ry[2] = LDY(r0 + 2);
    rx[3] = LDX(r0 + 3); ry[3] = LDY(r0 + 3);
    HROW(rx[0], ry[0], h0u, h0v, h0p, h0q, true);      // row r0
    HROW(rx[1], ry[1], h1u, h1v, h1p, h1q, true);      // row r0+1

#pragma unroll
    for (int i = 0; i < RPS; ++i) {
        // prefetch row r0+i+4 into slot i&3 (holds row r0+i, already consumed)
        int rn = r0 + i + 4; rn = (rn < HH) ? rn : (HH - 1);
        rx[i & 3] = LDX(rn); ry[i & 3] = LDY(rn);

        f4 hu, hv, hp, hq;
        HROW(rx[(i + 2) & 3], ry[(i + 2) & 3], hu, hv, hp, hq, (i <= RPS - 3));

        const f4 Su = h0u + h1u + hu;
        const f4 Sv = h0v + h1v + hv;
        const f4 Sp = h0p + h1p + hp;
        const f4 Sq = h0q + h1q + hq;

        // scaled SSIM (each factor x162): 4SxSy=Su^2-Sv^2, 2(Sx^2+Sy^2)=Su^2+Sv^2
        // 4Sxy=Sp-Sq, 2(Sxx+Syy)=Sp+Sq
        const f4 A  = Su * Su, B = Sv * Sv;
        const f4 d1 = A - B,   d2 = A + B;
        const f4 t1 = Sp - Sq, t2 = Sp + Sq;
        const f4 n1  = d1 + C1;
        const f4 n2  = 9.f * t1 - d1 + C2;
        const f4 p1v = d2 + C1;
        const f4 p2v = 9.f * t2 - d2 + C2;
        const f4 num = n1 * n2;
        const f4 den = p1v * p2v;
        f4 dd;
        dd.x = 0.5f - 0.5f * num.x * rcpf_(den.x);
        dd.y = 0.5f - 0.5f * num.y * rcpf_(den.y);
        dd.z = 0.5f - 0.5f * num.z * rcpf_(den.z);
        dd.w = 0.5f - 0.5f * num.w * rcpf_(den.w);
        dd.x = fminf(fmaxf(dd.x, 0.f), 1.f);
        dd.y = fminf(fmaxf(dd.y, 0.f), 1.f);
        dd.z = fminf(fmaxf(dd.z, 0.f), 1.f);
        dd.w = fminf(fmaxf(dd.w, 0.f), 1.f);

        if (r0 + i < OHH) accs += dd;                  // wave-uniform gate (last strip)

        h0u = h1u; h0v = h1v; h0p = h1p; h0q = h1q;
        h1u = hu;  h1v = hv;  h1p = hp;  h1q = hq;
    }
#undef HROW
#undef LDX
#undef LDY

    // epilogue ownership masks (recomputed — zero live registers in the loop)
    const int ssim_end = (chunk == 2) ? 638 : (a + 252);
    const int l1_end   = (chunk == 2) ? 640 : (a + 252);
    const float Lm = (c0 < l1_end) ? 1.f : 0.f;        // l1 mask is whole-lane (f4-aligned)
    f4 cm;
    cm.x = (c0 + 0 < ssim_end) ? 1.f : 0.f;
    cm.y = (c0 + 1 < ssim_end) ? 1.f : 0.f;
    cm.z = (c0 + 2 < ssim_end) ? 1.f : 0.f;
    cm.w = (c0 + 3 < ssim_end) ? 1.f : 0.f;

    float s = accs.x * cm.x + accs.y * cm.y + accs.z * cm.z + accs.w * cm.w;
    float l = (accl.x + accl.y + accl.z + accl.w) * Lm;
#pragma unroll
    for (int off = 32; off > 0; off >>= 1) {
        s += __shfl_down(s, off);
        l += __shfl_down(l, off);
    }
    __shared__ float sm[8];
    if (lane == 0) { sm[wv] = s; sm[4 + wv] = l; }
    __syncthreads();
    if (threadIdx.x == 0) {
        ws[bid0 * 2 + 0] = sm[0] + sm[1] + sm[2] + sm[3];
        ws[bid0 * 2 + 1] = sm[4] + sm[5] + sm[6] + sm[7];
    }
}

__global__ __launch_bounds__(256) void ssim_finalize(const float* __restrict__ ws,
                                                     float* __restrict__ out) {
    const int t = threadIdx.x;
    float s = 0.f, l = 0.f;
    for (int j = t; j < NBLOCKS; j += 256) {
        s += ws[2*j];
        l += ws[2*j + 1];
    }
#pragma unroll
    for (int off = 32; off > 0; off >>= 1) {
        s += __shfl_down(s, off);
        l += __shfl_down(l, off);
    }
    __shared__ float sm[8];
    const int w = t >> 6, lane = t & 63;
    if (lane == 0) { sm[w] = s; sm[4 + w] = l; }
    __syncthreads();
    if (t == 0) {
        float S = sm[0] + sm[1] + sm[2] + sm[3];
        float L = sm[4] + sm[5] + sm[6] + sm[7];
        out[0] = 0.85f * (S * (1.0f / 11698368.0f))
               + 0.15f * (L * (1.0f / 11796480.0f));
    }
}

extern "C" void kernel_launch(void* const* d_in, const int* in_sizes, int n_in,
                              void* d_out, int out_size, void* d_ws, size_t ws_size,
                              hipStream_t stream) {
    const float* images = (const float*)d_in[0];
    const float* recon  = (const float*)d_in[1];
    float* ws = (float*)d_ws;
    ssim_main<<<NBLOCKS, 256, 0, stream>>>(images, recon, ws);
    ssim_finalize<<<1, 256, 0, stream>>>(ws, (float*)d_out);
}